// Round 9
// baseline (132.471 us; speedup 1.0000x reference)
//
#include <hip/hip_runtime.h>
#include <math.h>

#define NN 5000      // nodes
#define NE 40000     // edges
#define UU 64        // hidden units
#define FE 16        // edge features
#define FEP 17       // +1 pseudo-feature for edge_bias
#define KD (FEP*UU)  // 1088
#define LDK (KD+8)   // padded LDS row (halfs); stride 548 dw == 4 mod 32
#define NSTEPS 4
#define NT 8         // nodes per step-tile (5000 % 8 == 0)
#define NB (NN/NT)   // 625 blocks
#define SLOT 40      // per-node edge bucket capacity (mean deg 8, P(>=40)~1e-15)
#define CH 8         // gather pipeline chunk
#define NPRE 8       // prefetched wb fragments (k = 0..256)
#define WBN (UU*KD)  // 69632
#define GTN (192*64) // 12288

typedef _Float16 half8 __attribute__((ext_vector_type(8)));
typedef float f32x4 __attribute__((ext_vector_type(4)));

__device__ __forceinline__ float sigm(float x){ return 1.f/(1.f + __expf(-x)); }
__device__ __forceinline__ int rfl(int x){ return __builtin_amdgcn_readfirstlane(x); }

// ---- build f16 weight tables + zero per-node degree counters ----
__global__ void build_k(const float* __restrict__ ek, const float* __restrict__ eb,
                        const float* __restrict__ gk, const float* __restrict__ rk,
                        _Float16* __restrict__ wb, _Float16* __restrict__ gkt,
                        _Float16* __restrict__ rkt, int* __restrict__ deg){
  int tid = blockIdx.x*blockDim.x + threadIdx.x;
  if (tid < NN) deg[tid] = 0;
  if (tid < WBN){
    int i = tid / KD, k = tid - i*KD;
    int f = k >> 6, j = k & 63;
    float v = (f < FE) ? ek[f*4096 + i*64 + j] : eb[i*64 + j];
    wb[tid] = (_Float16)v;
  } else if (tid < WBN + GTN){
    int r = tid - WBN; int n = r >> 6, k = r & 63;
    gkt[r] = (_Float16)gk[k*192 + n];
  } else if (tid < WBN + 2*GTN){
    int r = tid - WBN - GTN; int n = r >> 6, k = r & 63;
    rkt[r] = (_Float16)rk[k*192 + n];
  }
}

// ---- bucket edges by src (atomic slot alloc; order canonicalized in prep_k) ----
__global__ void bucket_k(const int* __restrict__ pair, int* __restrict__ deg,
                         int* __restrict__ eidb){
  int e = blockIdx.x*blockDim.x + threadIdx.x;
  if (e < NE){
    int v = pair[2*e];
    int pos = atomicAdd(&deg[v], 1);
    if (pos < SLOT) eidb[v*SLOT + pos] = e;
  }
}

// ---- canonical order via lane-parallel rank (edge ids unique) + resolve nbr ----
__global__ __launch_bounds__(512) void prep_k(const int* __restrict__ pair,
                       const int* __restrict__ deg,
                       const int* __restrict__ eidb, int2* __restrict__ enb){
  int w = threadIdx.x >> 6, lane = threadIdx.x & 63;
  int v = blockIdx.x * 8 + w;
  if (v >= NN) return;
  int dg = deg[v]; if (dg > SLOT) dg = SLOT;
  if (lane < dg){
    int e = eidb[v*SLOT + lane];
    int rank = 0;
    for (int j=0; j<dg; ++j){ int ej = eidb[v*SLOT + j]; rank += (ej < e); }
    enb[v*SLOT + rank] = make_int2(e, pair[2*e + 1]);
  }
}

// ---- fused step: wave-specialized pipeline ----
// all waves: gather 1 node.  waves 0-3: agg matmul (wb prefetch).
// waves 4-7: GRU recurrent concurrent with agg, then mx + gates + store.
__global__ __launch_bounds__(512, 4) void step_k(const float* __restrict__ h_in,
        float* __restrict__ h_out, const float* __restrict__ ef,
        const int* __restrict__ deg, const int2* __restrict__ enb,
        const _Float16* __restrict__ wb, const _Float16* __restrict__ gkt,
        const _Float16* __restrict__ rkt, const float* __restrict__ gb){
  __shared__ _Float16 Gs[NT*LDK];      // 17536 B
  __shared__ _Float16 aggT[NT*72];     // 1152 B
  __shared__ _Float16 hT[NT*72];       // 1152 B

  int tid = threadIdx.x;
  int w = tid >> 6, lane = tid & 63;
  int r16 = lane & 15, kh = lane >> 4;
  int vb = blockIdx.x * NT;
  int v  = vb + w;                     // this wave's node
  int uw2 = (w & 3)*16 + r16;          // unit owned in GRU phases (waves 4-7)

  // -- prefetches (independent of gather) --
  half8 bpre[NPRE];                    // waves 0-3: first NPRE wb fragments
  half8 wz0,wz1,wr0,wr1,wh0,wh1;      // waves 4-7: rkt fragments
  float b0z,b0r,b0h,b1z,b1r,b1h;
  if (w < 4){
    const _Float16* bp = wb + (size_t)(w*16 + r16)*KD + kh*8;
    #pragma unroll
    for (int i=0;i<NPRE;++i) bpre[i] = *(const half8*)(bp + i*32);
  } else {
    const _Float16* rz = rkt + (size_t)(      uw2)*64 + kh*8;
    const _Float16* rr = rkt + (size_t)( 64 + uw2)*64 + kh*8;
    const _Float16* rh = rkt + (size_t)(128 + uw2)*64 + kh*8;
    wz0 = *(const half8*)(rz); wz1 = *(const half8*)(rz + 32);
    wr0 = *(const half8*)(rr); wr1 = *(const half8*)(rr + 32);
    wh0 = *(const half8*)(rh); wh1 = *(const half8*)(rh + 32);
    b0z = gb[uw2];     b0r = gb[64+uw2];  b0h = gb[128+uw2];
    b1z = gb[192+uw2]; b1r = gb[256+uw2]; b1h = gb[320+uw2];
  }

  hT[w*72 + lane] = (_Float16)h_in[(size_t)v*64 + lane];

  // ---- gather: wave w owns node v (17 features, lane = unit) ----
  {
    int dgv = rfl(deg[v]); if (dgv > SLOT) dgv = SLOT;
    const int2* lst = enb + v*SLOT;
    float g[FEP];
    #pragma unroll
    for (int f=0;f<FEP;++f) g[f] = 0.f;
    for (int c0=0; c0<dgv; c0+=CH){
      int ee[CH], nb[CH];
      #pragma unroll
      for (int q=0;q<CH;++q){ int i=c0+q;
        if (i<dgv){ int2 p = lst[i]; ee[q]=rfl(p.x); nb[q]=rfl(p.y); }
        else { ee[q]=0; nb[q]=0; } }
      float hj[CH];
      #pragma unroll
      for (int q=0;q<CH;++q){ int i=c0+q;
        hj[q] = (i<dgv) ? h_in[(size_t)nb[q]*64 + lane] : 0.f; }
      #pragma unroll
      for (int q=0;q<CH;++q){ int i=c0+q;
        if (i<dgv){
          const float4* er = (const float4*)(ef + (size_t)ee[q]*FE);
          float4 e0 = er[0], e1 = er[1], e2 = er[2], e3 = er[3];
          g[ 0]=fmaf(e0.x,hj[q],g[ 0]); g[ 1]=fmaf(e0.y,hj[q],g[ 1]);
          g[ 2]=fmaf(e0.z,hj[q],g[ 2]); g[ 3]=fmaf(e0.w,hj[q],g[ 3]);
          g[ 4]=fmaf(e1.x,hj[q],g[ 4]); g[ 5]=fmaf(e1.y,hj[q],g[ 5]);
          g[ 6]=fmaf(e1.z,hj[q],g[ 6]); g[ 7]=fmaf(e1.w,hj[q],g[ 7]);
          g[ 8]=fmaf(e2.x,hj[q],g[ 8]); g[ 9]=fmaf(e2.y,hj[q],g[ 9]);
          g[10]=fmaf(e2.z,hj[q],g[10]); g[11]=fmaf(e2.w,hj[q],g[11]);
          g[12]=fmaf(e3.x,hj[q],g[12]); g[13]=fmaf(e3.y,hj[q],g[13]);
          g[14]=fmaf(e3.z,hj[q],g[14]); g[15]=fmaf(e3.w,hj[q],g[15]);
          g[16] += hj[q];
        } }
    }
    #pragma unroll
    for (int f=0;f<FEP;++f) Gs[w*LDK + f*64 + lane] = (_Float16)g[f];
  }
  __syncthreads();

  f32x4 mhz={0.f,0.f,0.f,0.f}, mhr=mhz, mhh=mhz;
  half8 gz0,gz1,gr0,gr1,gh0,gh1;       // gkt fragments (loaded during phase 2)

  if (w < 4){
    // ---- agg matmul: cols w*16..w*16+15; A rows 0-7 valid ----
    f32x4 acc = {0.f,0.f,0.f,0.f};
    const _Float16* ap = Gs + (r16 & 7)*LDK + kh*8;
    const _Float16* bp = wb + (size_t)(w*16 + r16)*KD + kh*8;
    #pragma unroll
    for (int i=0;i<NPRE;++i){
      half8 a = *(const half8*)(ap + i*32);
      acc = __builtin_amdgcn_mfma_f32_16x16x32_f16(a, bpre[i], acc, 0, 0, 0);
    }
    #pragma unroll 4
    for (int k0=NPRE*32; k0<KD; k0+=32){
      half8 a = *(const half8*)(ap + k0);
      half8 b = *(const half8*)(bp + k0);
      acc = __builtin_amdgcn_mfma_f32_16x16x32_f16(a, b, acc, 0, 0, 0);
    }
    if (kh < 2){           // C rows 0-7 live in kh 0,1 (row = kh*4+r)
      #pragma unroll
      for (int r=0;r<4;++r) aggT[(kh*4+r)*72 + w*16 + r16] = (_Float16)acc[r];
    }
  } else {
    // ---- GRU recurrent: mh = hT @ rkt (prefetched weights, zero latency) ----
    const _Float16* ah = hT + (r16 & 7)*72 + kh*8;
    half8 h0 = *(const half8*)(ah);
    half8 h1 = *(const half8*)(ah + 32);
    mhz = __builtin_amdgcn_mfma_f32_16x16x32_f16(h0, wz0, mhz, 0,0,0);
    mhz = __builtin_amdgcn_mfma_f32_16x16x32_f16(h1, wz1, mhz, 0,0,0);
    mhr = __builtin_amdgcn_mfma_f32_16x16x32_f16(h0, wr0, mhr, 0,0,0);
    mhr = __builtin_amdgcn_mfma_f32_16x16x32_f16(h1, wr1, mhr, 0,0,0);
    mhh = __builtin_amdgcn_mfma_f32_16x16x32_f16(h0, wh0, mhh, 0,0,0);
    mhh = __builtin_amdgcn_mfma_f32_16x16x32_f16(h1, wh1, mhh, 0,0,0);
    // issue gkt prefetch now; lands across the barrier
    const _Float16* gz = gkt + (size_t)(      uw2)*64 + kh*8;
    const _Float16* gr = gkt + (size_t)( 64 + uw2)*64 + kh*8;
    const _Float16* gh = gkt + (size_t)(128 + uw2)*64 + kh*8;
    gz0 = *(const half8*)(gz); gz1 = *(const half8*)(gz + 32);
    gr0 = *(const half8*)(gr); gr1 = *(const half8*)(gr + 32);
    gh0 = *(const half8*)(gh); gh1 = *(const half8*)(gh + 32);
  }
  __syncthreads();

  // ---- waves 4-7: mx = aggT @ gkt; combine with in-register mh; gates; store ----
  if (w >= 4){
    const _Float16* az = aggT + (r16 & 7)*72 + kh*8;
    half8 a0 = *(const half8*)(az);
    half8 a1 = *(const half8*)(az + 32);
    f32x4 mxz={0.f,0.f,0.f,0.f}, mxr=mxz, mxh=mxz;
    mxz = __builtin_amdgcn_mfma_f32_16x16x32_f16(a0, gz0, mxz, 0,0,0);
    mxz = __builtin_amdgcn_mfma_f32_16x16x32_f16(a1, gz1, mxz, 0,0,0);
    mxr = __builtin_amdgcn_mfma_f32_16x16x32_f16(a0, gr0, mxr, 0,0,0);
    mxr = __builtin_amdgcn_mfma_f32_16x16x32_f16(a1, gr1, mxr, 0,0,0);
    mxh = __builtin_amdgcn_mfma_f32_16x16x32_f16(a0, gh0, mxh, 0,0,0);
    mxh = __builtin_amdgcn_mfma_f32_16x16x32_f16(a1, gh1, mxh, 0,0,0);
    if (kh < 2){
      #pragma unroll
      for (int r=0;r<4;++r){
        int row = vb + kh*4 + r;
        float z  = sigm(mxz[r] + b0z + mhz[r] + b1z);
        float rr = sigm(mxr[r] + b0r + mhr[r] + b1r);
        float hc = tanhf(mxh[r] + b0h + rr*(mhh[r] + b1h));
        float hold = h_in[(size_t)row*64 + uw2];
        h_out[(size_t)row*64 + uw2] = z*hold + (1.f - z)*hc;
      }
    }
  }
}

extern "C" void kernel_launch(void* const* d_in, const int* in_sizes, int n_in,
                              void* d_out, int out_size, void* d_ws, size_t ws_size,
                              hipStream_t stream){
  const float* nodef = (const float*)d_in[0];
  const float* edgef = (const float*)d_in[1];
  const int*   pair  = (const int*)  d_in[2];
  const float* ek    = (const float*)d_in[3];
  const float* ebias = (const float*)d_in[4];
  const float* gk    = (const float*)d_in[5];
  const float* rk    = (const float*)d_in[6];
  const float* gb    = (const float*)d_in[7];

  char* ws = (char*)d_ws;
  size_t o = 0;
  auto carve = [&](size_t bytes)->char*{
    char* p = ws + o; o = (o + bytes + 255) & ~255ULL; return p; };
  int*      deg  = (int*)     carve(NN*sizeof(int));
  int*      eidb = (int*)     carve((size_t)NN*SLOT*sizeof(int));
  int2*     enb  = (int2*)    carve((size_t)NN*SLOT*sizeof(int2));
  _Float16* wb   = (_Float16*)carve((size_t)WBN*sizeof(_Float16));
  _Float16* gkt  = (_Float16*)carve((size_t)GTN*sizeof(_Float16));
  _Float16* rkt  = (_Float16*)carve((size_t)GTN*sizeof(_Float16));
  float*    hA   = (float*)   carve((size_t)NN*UU*sizeof(float));
  float*    hB   = (float*)   carve((size_t)NN*UU*sizeof(float));

  build_k <<<(WBN+2*GTN+255)/256, 256, 0, stream>>>(ek, ebias, gk, rk, wb, gkt, rkt, deg);
  bucket_k<<<(NE+255)/256, 256, 0, stream>>>(pair, deg, eidb);
  prep_k  <<<NB, 512, 0, stream>>>(pair, deg, eidb, enb);

  const float* hin = nodef;
  for (int s=0; s<NSTEPS; ++s){
    float* hout = (s == NSTEPS-1) ? (float*)d_out : ((s & 1) ? hB : hA);
    step_k<<<NB, 512, 0, stream>>>(hin, hout, edgef, deg, enb,
                                   wb, gkt, rkt, gb);
    hin = hout;
  }
}